// Round 1
// baseline (431.656 us; speedup 1.0000x reference)
//
#include <hip/hip_runtime.h>
#include <math.h>

#define M 16
#define KD 1024
#define CS_EPS 1e-6f

#define N0 (1024 * 1024)          // elements in rec0
#define N1 (1024 * 4096)          // elements in rec1
#define N40 (N0 / 4)              // float4 count, V0 slot
#define N41 (N1 / 4)              // float4 count, V1 slot

// ---------------------------------------------------------------------------
// Kernel 1: cosine similarity of task_emb vs each of M keys, softmax -> w[M]
// 1024 threads = 16 waves; wave m owns memory slot m.
// ---------------------------------------------------------------------------
__global__ __launch_bounds__(1024) void addr_head_kernel(
    const float* __restrict__ task_emb,   // [KD]
    const float* __restrict__ K_memory,   // [M, KD]
    float* __restrict__ w_out)            // [M]
{
    __shared__ float s_cos[M];
    const int lane = threadIdx.x & 63;
    const int wave = threadIdx.x >> 6;    // 0..15 == slot index

    float dot = 0.f, n2sq = 0.f, n1sq = 0.f;
#pragma unroll
    for (int k = 0; k < KD / 64; ++k) {
        float t  = task_emb[lane + k * 64];
        float km = K_memory[wave * KD + lane + k * 64];
        dot  += t * km;
        n2sq += km * km;
        n1sq += t * t;      // redundant per wave; trivial cost
    }
#pragma unroll
    for (int off = 32; off; off >>= 1) {
        dot  += __shfl_down(dot,  off, 64);
        n2sq += __shfl_down(n2sq, off, 64);
        n1sq += __shfl_down(n1sq, off, 64);
    }
    if (lane == 0) {
        float denom = fmaxf(sqrtf(n1sq) * sqrtf(n2sq), CS_EPS);
        s_cos[wave] = dot / denom;
    }
    __syncthreads();
    if (threadIdx.x == 0) {
        float mx = -1e30f;
#pragma unroll
        for (int m = 0; m < M; ++m) mx = fmaxf(mx, s_cos[m]);
        float e[M];
        float sum = 0.f;
#pragma unroll
        for (int m = 0; m < M; ++m) { e[m] = expf(s_cos[m] - mx); sum += e[m]; }
        float inv = 1.f / sum;
#pragma unroll
        for (int m = 0; m < M; ++m) w_out[m] = e[m] * inv;
    }
}

// ---------------------------------------------------------------------------
// Kernel 2: out[idx] = sum_m w[m] * V[m][idx], fused over both V0 and V1.
// One thread per float4. Per-block the V0/V1 branch is uniform
// (N40 = 262144 is a multiple of 256).
// ---------------------------------------------------------------------------
__global__ __launch_bounds__(256) void wsum_kernel(
    const float4* __restrict__ V0,
    const float4* __restrict__ V1,
    const float* __restrict__ w,
    float4* __restrict__ out)
{
    int idx = blockIdx.x * 256 + threadIdx.x;

    const float4* __restrict__ V;
    float4* __restrict__ o;
    long long pitch;   // slot pitch in float4s
    if (idx < N40) {
        V = V0; o = out; pitch = N40;
    } else {
        idx -= N40;
        V = V1; o = out + N40; pitch = N41;
    }

    float wl[M];
#pragma unroll
    for (int m = 0; m < M; ++m) wl[m] = w[m];   // broadcast, L1-hot

    float4 acc = make_float4(0.f, 0.f, 0.f, 0.f);
#pragma unroll
    for (int m = 0; m < M; ++m) {
        float4 v = V[(long long)m * pitch + idx];
        acc.x = fmaf(wl[m], v.x, acc.x);
        acc.y = fmaf(wl[m], v.y, acc.y);
        acc.z = fmaf(wl[m], v.z, acc.z);
        acc.w = fmaf(wl[m], v.w, acc.w);
    }
    o[idx] = acc;
}

extern "C" void kernel_launch(void* const* d_in, const int* in_sizes, int n_in,
                              void* d_out, int out_size, void* d_ws, size_t ws_size,
                              hipStream_t stream) {
    const float* task_emb = (const float*)d_in[0];   // [1,1024]
    const float* K_memory = (const float*)d_in[1];   // [16,1024]
    const float* V0       = (const float*)d_in[2];   // [16,1024,1024]
    const float* V1       = (const float*)d_in[3];   // [16,1024,4096]
    float* w   = (float*)d_ws;                       // 16 floats scratch
    float* out = (float*)d_out;                      // [N0 + N1]

    addr_head_kernel<<<1, 1024, 0, stream>>>(task_emb, K_memory, w);

    const int total4 = N40 + N41;                    // 1,310,720 float4s
    wsum_kernel<<<total4 / 256, 256, 0, stream>>>(
        (const float4*)V0, (const float4*)V1, w, (float4*)out);
}

// Round 3
// 386.843 us; speedup vs baseline: 1.1158x; 1.1158x over previous
//
#include <hip/hip_runtime.h>
#include <math.h>

#define M 16
#define KD 1024
#define CS_EPS 1e-6f

#define N0 (1024 * 1024)          // elements in rec0
#define N1 (1024 * 4096)          // elements in rec1
#define N40 (N0 / 4)              // float4 count, V0 slot  = 262144
#define N41 (N1 / 4)              // float4 count, V1 slot  = 1048576

typedef float vf4 __attribute__((ext_vector_type(4)));   // native vec for NT builtins

// ---------------------------------------------------------------------------
// Kernel 1: cosine similarity of task_emb vs each of M keys, softmax -> w[M]
// ---------------------------------------------------------------------------
__global__ __launch_bounds__(1024) void addr_head_kernel(
    const float* __restrict__ task_emb,   // [KD]
    const float* __restrict__ K_memory,   // [M, KD]
    float* __restrict__ w_out)            // [M]
{
    __shared__ float s_cos[M];
    const int lane = threadIdx.x & 63;
    const int wave = threadIdx.x >> 6;    // 0..15 == slot index

    float dot = 0.f, n2sq = 0.f, n1sq = 0.f;
#pragma unroll
    for (int k = 0; k < KD / 64; ++k) {
        float t  = task_emb[lane + k * 64];
        float km = K_memory[wave * KD + lane + k * 64];
        dot  += t * km;
        n2sq += km * km;
        n1sq += t * t;
    }
#pragma unroll
    for (int off = 32; off; off >>= 1) {
        dot  += __shfl_down(dot,  off, 64);
        n2sq += __shfl_down(n2sq, off, 64);
        n1sq += __shfl_down(n1sq, off, 64);
    }
    if (lane == 0) {
        float denom = fmaxf(sqrtf(n1sq) * sqrtf(n2sq), CS_EPS);
        s_cos[wave] = dot / denom;
    }
    __syncthreads();
    if (threadIdx.x == 0) {
        float mx = -1e30f;
#pragma unroll
        for (int m = 0; m < M; ++m) mx = fmaxf(mx, s_cos[m]);
        float e[M];
        float sum = 0.f;
#pragma unroll
        for (int m = 0; m < M; ++m) { e[m] = expf(s_cos[m] - mx); sum += e[m]; }
        float inv = 1.f / sum;
#pragma unroll
        for (int m = 0; m < M; ++m) w_out[m] = e[m] * inv;
    }
}

// ---------------------------------------------------------------------------
// Kernel 2: out[i] = sum_m w[m] * V[m][i]
//   - PITCH4 compile-time -> slot bases become SGPR constants
//   - 4 vf4 outputs per thread, block-strided -> 4 indep loads per m-step
//   - weights broadcast to SGPRs via readfirstlane
//   - non-temporal: streams are read-once / write-once
// ---------------------------------------------------------------------------
__device__ __forceinline__ float sgpr_bcast(float x) {
    return __int_as_float(__builtin_amdgcn_readfirstlane(__float_as_int(x)));
}

template<int PITCH4>
__device__ __forceinline__ void wsum_body(
    const vf4* __restrict__ V,
    const float* __restrict__ w,
    vf4* __restrict__ out,
    int blk)
{
    const long long base = (long long)blk * 1024 + threadIdx.x;

    float ws[M];
#pragma unroll
    for (int m = 0; m < M; ++m) ws[m] = sgpr_bcast(w[m]);

    vf4 acc[4];
#pragma unroll
    for (int j = 0; j < 4; ++j) acc[j] = (vf4)(0.f);

#pragma unroll
    for (int m = 0; m < M; ++m) {
        const vf4* __restrict__ p = V + (long long)m * PITCH4 + base;
        vf4 v[4];
#pragma unroll
        for (int j = 0; j < 4; ++j) v[j] = __builtin_nontemporal_load(p + j * 256);
#pragma unroll
        for (int j = 0; j < 4; ++j) {
            acc[j].x = fmaf(ws[m], v[j].x, acc[j].x);
            acc[j].y = fmaf(ws[m], v[j].y, acc[j].y);
            acc[j].z = fmaf(ws[m], v[j].z, acc[j].z);
            acc[j].w = fmaf(ws[m], v[j].w, acc[j].w);
        }
    }
#pragma unroll
    for (int j = 0; j < 4; ++j)
        __builtin_nontemporal_store(acc[j], &out[base + j * 256]);
}

__global__ __launch_bounds__(256) void wsum_kernel(
    const vf4* __restrict__ V0,
    const vf4* __restrict__ V1,
    const float* __restrict__ w,
    vf4* __restrict__ out)
{
    const int b = blockIdx.x;
    if (b < N40 / 1024) {                       // 256 blocks -> V0
        wsum_body<N40>(V0, w, out, b);
    } else {                                    // 1024 blocks -> V1
        wsum_body<N41>(V1, w, out + N40, b - N40 / 1024);
    }
}

extern "C" void kernel_launch(void* const* d_in, const int* in_sizes, int n_in,
                              void* d_out, int out_size, void* d_ws, size_t ws_size,
                              hipStream_t stream) {
    const float* task_emb = (const float*)d_in[0];   // [1,1024]
    const float* K_memory = (const float*)d_in[1];   // [16,1024]
    const float* V0       = (const float*)d_in[2];   // [16,1024,1024]
    const float* V1       = (const float*)d_in[3];   // [16,1024,4096]
    float* w   = (float*)d_ws;                       // 16 floats scratch
    float* out = (float*)d_out;                      // [N0 + N1]

    addr_head_kernel<<<1, 1024, 0, stream>>>(task_emb, K_memory, w);

    const int nblk = (N40 + N41) / 1024;             // 1280 blocks
    wsum_kernel<<<nblk, 256, 0, stream>>>(
        (const vf4*)V0, (const vf4*)V1, w, (vf4*)out);
}